// Round 1
// baseline (516.366 us; speedup 1.0000x reference)
//
#include <hip/hip_runtime.h>

// ManifoldConstrainedHyperConnection fused kernel.
// Shapes: x (8192 tokens, 4 streams, 2048 dim) fp32; W_router (24, 2048); b_router (24).
// out (8192, 4, 2048) fp32.
//
// One token per 256-thread block. Each thread owns 8 d-columns of all 4 streams
// (two float4 chunks per stream) in registers -> x read exactly once from HBM.
// Router logits via per-thread partial dots + shfl_xor wave reduce + LDS cross-wave.
// Sinkhorn on lanes 0..15 of wave 0 via 16-lane shuffles. M = residual + post*pre
// broadcast through LDS; output = M (4x4) applied to the register-resident x slice.

#define SINKHORN_ITERS 4
#define EPSV 1e-6f

__global__ __launch_bounds__(256, 4) void mchc_fused(
    const float* __restrict__ x,
    const float* __restrict__ Wr,
    const float* __restrict__ br,
    float* __restrict__ out)
{
    const int token = blockIdx.x;      // 0..8191
    const int tid   = threadIdx.x;     // 0..255
    const int lane  = tid & 63;
    const int wave  = tid >> 6;

    const float4* __restrict__ x4 = (const float4*)(x + (size_t)token * 8192);
    const float4* __restrict__ w4 = (const float4*)Wr;
    float4*       __restrict__ o4 = (float4*)(out + (size_t)token * 8192);

    // ---- load x token slice into registers: xa[w] = chunk tid, xb[w] = chunk tid+256
    float4 xa[4], xb[4];
#pragma unroll
    for (int w = 0; w < 4; ++w) {
        xa[w] = x4[w * 512 + tid];
        xb[w] = x4[w * 512 + 256 + tid];
    }

    // stream-sum (mean * 4; fold the 0.25 into the final logits)
    float4 sa, sb;
    sa.x = xa[0].x + xa[1].x + xa[2].x + xa[3].x;
    sa.y = xa[0].y + xa[1].y + xa[2].y + xa[3].y;
    sa.z = xa[0].z + xa[1].z + xa[2].z + xa[3].z;
    sa.w = xa[0].w + xa[1].w + xa[2].w + xa[3].w;
    sb.x = xb[0].x + xb[1].x + xb[2].x + xb[3].x;
    sb.y = xb[0].y + xb[1].y + xb[2].y + xb[3].y;
    sb.z = xb[0].z + xb[1].z + xb[2].z + xb[3].z;
    sb.w = xb[0].w + xb[1].w + xb[2].w + xb[3].w;

    // ---- 24 router partial dots (W_router is L2-resident)
    float p[24];
#pragma unroll
    for (int k = 0; k < 24; ++k) {
        float4 wa = w4[k * 512 + tid];
        float4 wb = w4[k * 512 + 256 + tid];
        p[k] = sa.x * wa.x + sa.y * wa.y + sa.z * wa.z + sa.w * wa.w
             + sb.x * wb.x + sb.y * wb.y + sb.z * wb.z + sb.w * wb.w;
    }

    // ---- reduce 24 values across the wave (butterfly), then across 4 waves via LDS
    __shared__ float red[4][24];
    __shared__ float rawbuf[24];
    __shared__ float Mbuf[16];

#pragma unroll
    for (int k = 0; k < 24; ++k) {
        float v = p[k];
        v += __shfl_xor(v, 1);
        v += __shfl_xor(v, 2);
        v += __shfl_xor(v, 4);
        v += __shfl_xor(v, 8);
        v += __shfl_xor(v, 16);
        v += __shfl_xor(v, 32);
        p[k] = v;
    }
    if (lane == 0) {
#pragma unroll
        for (int k = 0; k < 24; ++k) red[wave][k] = p[k];
    }
    __syncthreads();

    if (tid < 24) {
        float r = red[0][tid] + red[1][tid] + red[2][tid] + red[3][tid];
        rawbuf[tid] = 0.25f * r + br[tid];   // mean over W folded in here
    }
    __syncthreads();

    // ---- lanes 0..15 of wave 0: softmaxes + sinkhorn + fold post*pre
    if (tid < 16) {
        const int i = tid >> 2, j = tid & 3;

        float r0 = rawbuf[0], r1 = rawbuf[1], r2 = rawbuf[2], r3 = rawbuf[3];
        float mp = fmaxf(fmaxf(r0, r1), fmaxf(r2, r3));
        float sp = __expf(r0 - mp) + __expf(r1 - mp) + __expf(r2 - mp) + __expf(r3 - mp);
        float pre_j = __expf(rawbuf[j] - mp) / sp;

        float q0 = rawbuf[4], q1 = rawbuf[5], q2 = rawbuf[6], q3 = rawbuf[7];
        float mq = fmaxf(fmaxf(q0, q1), fmaxf(q2, q3));
        float sq = __expf(q0 - mq) + __expf(q1 - mq) + __expf(q2 - mq) + __expf(q3 - mq);
        float post_i = __expf(rawbuf[4 + i] - mq) / sq;

        // residual logits + (-2 off-diag, +2 diag) bias, exponentiate
        float w = __expf(rawbuf[8 + tid] + ((i == j) ? 2.0f : -2.0f));
#pragma unroll
        for (int it = 0; it < SINKHORN_ITERS; ++it) {
            // row normalize: sum over j (lanes differing in bits 0..1)
            float rs = w + __shfl_xor(w, 1);
            rs += __shfl_xor(rs, 2);
            w /= fmaxf(rs, EPSV);
            // col normalize: sum over i (lanes differing in bits 2..3)
            float cs = w + __shfl_xor(w, 4);
            cs += __shfl_xor(cs, 8);
            w /= fmaxf(cs, EPSV);
        }
        Mbuf[tid] = w + post_i * pre_j;   // fold post[i]*pre[j] into the 4x4 mix
    }
    __syncthreads();

    // ---- apply the 4x4 mix to the register-resident x slice
    float M[16];
#pragma unroll
    for (int m = 0; m < 16; ++m) M[m] = Mbuf[m];

#pragma unroll
    for (int i = 0; i < 4; ++i) {
        float m0 = M[i * 4 + 0], m1 = M[i * 4 + 1], m2 = M[i * 4 + 2], m3 = M[i * 4 + 3];
        float4 oa, ob;
        oa.x = m0 * xa[0].x + m1 * xa[1].x + m2 * xa[2].x + m3 * xa[3].x;
        oa.y = m0 * xa[0].y + m1 * xa[1].y + m2 * xa[2].y + m3 * xa[3].y;
        oa.z = m0 * xa[0].z + m1 * xa[1].z + m2 * xa[2].z + m3 * xa[3].z;
        oa.w = m0 * xa[0].w + m1 * xa[1].w + m2 * xa[2].w + m3 * xa[3].w;
        ob.x = m0 * xb[0].x + m1 * xb[1].x + m2 * xb[2].x + m3 * xb[3].x;
        ob.y = m0 * xb[0].y + m1 * xb[1].y + m2 * xb[2].y + m3 * xb[3].y;
        ob.z = m0 * xb[0].z + m1 * xb[1].z + m2 * xb[2].z + m3 * xb[3].z;
        ob.w = m0 * xb[0].w + m1 * xb[1].w + m2 * xb[2].w + m3 * xb[3].w;
        o4[i * 512 + tid]       = oa;
        o4[i * 512 + 256 + tid] = ob;
    }
}

extern "C" void kernel_launch(void* const* d_in, const int* in_sizes, int n_in,
                              void* d_out, int out_size, void* d_ws, size_t ws_size,
                              hipStream_t stream) {
    const float* x  = (const float*)d_in[0];
    const float* Wr = (const float*)d_in[1];
    const float* br = (const float*)d_in[2];
    float* out = (float*)d_out;

    const int tokens = in_sizes[0] / (4 * 2048);   // B*T = 8192
    mchc_fused<<<dim3(tokens), dim3(256), 0, stream>>>(x, Wr, br, out);
}